// Round 5
// baseline (69.874 us; speedup 1.0000x reference)
//
#include <hip/hip_runtime.h>
#include <math.h>

#define BB 8
#define NN 2048
#define INC 256
#define CC 128
#define NE 65536
#define CAP 128
#define MROWS (BB*NN)
#define BN_EPS 1e-5f
#define NT 9              // output col-tiles of 16 (8 -> hm, 1 -> s+pad)
#define NKC 8             // K chunks of 32 (K=256)
#define NFRAG (NT*NKC*64) // 4608 pre-packed fragments
#define FPSCALE 4194304.0 // 2^22 fixed-point scale for deterministic BN atomics

typedef unsigned int uint32;
typedef unsigned long long u64;
typedef __attribute__((ext_vector_type(8))) short short8;
typedef __attribute__((ext_vector_type(4))) float f32x4;

__device__ inline ushort f2bf(float f) {
  uint32 u = __float_as_uint(f);
  u += 0x7fffu + ((u >> 16) & 1u);
  return (ushort)(u >> 16);
}
__device__ inline float bf2f(ushort h) {
  return __uint_as_float(((uint32)h) << 16);
}

__device__ inline void load_edge(const void* ei, int is64, int e, int& s, int& d) {
  if (is64) {
    const long long* p = (const long long*)ei;
    s = (int)p[e]; d = (int)p[NE + e];
  } else {
    const int* p = (const int*)ei;
    s = p[e]; d = p[NE + e];
  }
}

// ---- prep: W -> packed MFMA fragments; detect int64; zero row_cnt + bins ----
// block m owns input rows [8m, 8m+8) == fragment k-slice (kc=m>>2, g=m&3).
__global__ __launch_bounds__(256) void k_prep(const float* __restrict__ W,
                                              const float* __restrict__ a,
                                              const int* __restrict__ ei32,
                                              uint4* __restrict__ pack,
                                              int* __restrict__ flag,
                                              int* __restrict__ row_cnt,
                                              u64* __restrict__ bins) {
  __shared__ float Wl[8][520];
  __shared__ float Wms[8][132];
  __shared__ float Was[8][8];
  __shared__ float av[256];
  int m = blockIdx.x, tid = threadIdx.x;
  if (m < 8) row_cnt[m * 256 + tid] = 0;
  if (m == 8) {
    #pragma unroll
    for (int i = 0; i < 8; ++i) bins[tid * 8 + i] = 0ull;
  }
  if (m == 0 && tid == 0) {
    int nz = 0;
    for (int t = 1; t < 128; t += 2) nz |= (ei32[t] != 0);
    *flag = nz ? 0 : 1;      // 1 => int64 layout
  }
  av[tid] = a[tid];
  const float4* Wg = (const float4*)(W + (size_t)m * 8 * 512);
  #pragma unroll
  for (int i = 0; i < 4; ++i) {
    int idx = tid + i * 256;           // 0..1023 float4s = 8 rows x 128
    int r = idx >> 7, c4 = idx & 127;
    *(float4*)&Wl[r][c4 * 4] = Wg[idx];
  }
  __syncthreads();
  {
    int c = tid & 127, half = tid >> 7;
    #pragma unroll
    for (int ii = 0; ii < 4; ++ii) {
      int r = half * 4 + ii;
      Wms[r][c] = 0.25f * (Wl[r][c] + Wl[r][128 + c] + Wl[r][256 + c] + Wl[r][384 + c]);
    }
  }
  {
    int i8 = tid >> 5, c2 = tid & 31;
    float p[8];
    #pragma unroll
    for (int j = 0; j < 8; ++j) p[j] = 0.0f;
    #pragma unroll
    for (int t4 = 0; t4 < 4; ++t4) {
      int cc = c2 + t4 * 32;
      float asrc = av[cc], adst = av[128 + cc];
      #pragma unroll
      for (int h = 0; h < 4; ++h) {
        float w = Wl[i8][h * 128 + cc];
        p[h] += w * asrc;
        p[4 + h] += w * adst;
      }
    }
    #pragma unroll
    for (int off = 16; off > 0; off >>= 1)
      #pragma unroll
      for (int j = 0; j < 8; ++j) p[j] += __shfl_xor(p[j], off, 64);
    if (c2 < 8) Was[i8][c2] = p[c2];
  }
  __syncthreads();
  if (tid < 144) {
    int t = tid >> 4, l16 = tid & 15;
    int cch = t * 16 + l16;
    int kc = m >> 2, g = m & 3;
    uint32 h[8];
    #pragma unroll
    for (int j = 0; j < 8; ++j) {
      float v = 0.0f;
      if (cch < CC) v = Wms[j][cch];
      else if (cch < CC + 8) v = Was[j][cch - CC];
      h[j] = (uint32)f2bf(v);
    }
    uint4 u;
    u.x = h[0] | (h[1] << 16);
    u.y = h[2] | (h[3] << 16);
    u.z = h[4] | (h[5] << 16);
    u.w = h[6] | (h[7] << 16);
    pack[(t * NKC + kc) * 64 + g * 16 + l16] = u;
  }
}

// ---- MFMA GEMM + edge-list build ----
// hm(bf16)[16384][128] = x @ Wm ; s(f32)[16384][8] = x @ Wa ; row lists from ei.
__global__ __launch_bounds__(256) void k_gemm(const float* __restrict__ x,
                                              const uint4* __restrict__ pack,
                                              const void* __restrict__ ei,
                                              const int* __restrict__ flag,
                                              ushort* __restrict__ hm,
                                              float* __restrict__ s,
                                              int* __restrict__ row_cnt,
                                              int* __restrict__ row_src) {
  int tid = threadIdx.x;
  // edge-list build: this block's 256 edges (independent of MFMA part)
  {
    int e = blockIdx.x * 256 + tid;
    int is64 = *flag;
    int src, dst;
    load_edge(ei, is64, e, src, dst);
    int pos = atomicAdd(&row_cnt[dst], 1);
    if (pos < CAP) row_src[dst * CAP + pos] = src;
  }

  int lane = tid & 63, wv = tid >> 6;
  int g = lane >> 4;
  int xrow = blockIdx.x * 64 + wv * 16 + (lane & 15);
  const float* xr = x + (size_t)xrow * INC;

  short8 xf[8];
  #pragma unroll
  for (int kc = 0; kc < 8; ++kc) {
    f32x4 xa = *(const f32x4*)(xr + kc * 32 + g * 8);
    f32x4 xb = *(const f32x4*)(xr + kc * 32 + g * 8 + 4);
    short8 t;
    t[0] = (short)f2bf(xa[0]); t[1] = (short)f2bf(xa[1]);
    t[2] = (short)f2bf(xa[2]); t[3] = (short)f2bf(xa[3]);
    t[4] = (short)f2bf(xb[0]); t[5] = (short)f2bf(xb[1]);
    t[6] = (short)f2bf(xb[2]); t[7] = (short)f2bf(xb[3]);
    xf[kc] = t;
  }

  f32x4 acc[NT];
  #pragma unroll
  for (int t = 0; t < NT; ++t) acc[t] = (f32x4)(0.0f);

  const short8* fr = (const short8*)pack;
  #pragma unroll
  for (int kc = 0; kc < NKC; ++kc) {
    #pragma unroll
    for (int t = 0; t < NT; ++t) {
      short8 af = fr[(t * NKC + kc) * 64 + lane];
      acc[t] = __builtin_amdgcn_mfma_f32_16x16x32_bf16(af, xf[kc], acc[t], 0, 0, 0);
    }
  }

  // D layout: row(ch-in-tile) = 4*g + reg, col(xrow-in-wave) = lane&15
  ushort* hrow = hm + (size_t)xrow * CC;
  #pragma unroll
  for (int t = 0; t < 8; ++t) {
    uint32 p0 = (uint32)f2bf(acc[t][0]) | ((uint32)f2bf(acc[t][1]) << 16);
    uint32 p1 = (uint32)f2bf(acc[t][2]) | ((uint32)f2bf(acc[t][3]) << 16);
    *(uint2*)(hrow + t * 16 + g * 4) = make_uint2(p0, p1);
  }
  if (g < 2) {
    *(f32x4*)(s + (size_t)xrow * 8 + g * 4) = acc[8];
  }
}

__device__ inline float edge_e(f32x4 ss, f32x4 sd) {
  float sum = 0.0f;
  #pragma unroll
  for (int h = 0; h < 4; ++h) {
    float v = ss[h] + sd[h];
    sum += (v > 0.0f) ? v : 0.2f * v;
  }
  return 0.25f * sum;
}

// ---- fused dedupe+sort+e+softmax+aggregate+BN-partials: one block per dst row ----
__global__ __launch_bounds__(256) void k_agg(const int* __restrict__ row_cnt,
                                             const int* __restrict__ row_src,
                                             const float* __restrict__ s,
                                             const uint32* __restrict__ hm32,
                                             uint32* __restrict__ hout,
                                             u64* __restrict__ bins) {
  __shared__ int rsrc[CAP], csrc[CAP];
  __shared__ float swgt[4][CAP];
  __shared__ f32x4 red[256];
  __shared__ int wcnt[2];
  int d = blockIdx.x, tid = threadIdx.x;
  int lane = tid & 63, wv = tid >> 6;
  int k0 = row_cnt[d]; if (k0 > CAP) k0 = CAP;

  if (tid < k0) rsrc[tid] = row_src[d * CAP + tid];
  __syncthreads();
  // dedupe by src (duplicate (src,dst) edges have identical e-values; set suffices)
  int keep = 0;
  if (tid < k0) {
    keep = 1;
    int sv = rsrc[tid];
    for (int q = 0; q < tid; ++q) if (rsrc[q] == sv) { keep = 0; break; }
  }
  u64 mask = __ballot(keep);
  int pos = __popcll(mask & ((1ull << lane) - 1ull));
  if (lane == 0 && wv < 2) wcnt[wv] = (int)__popcll(mask);
  __syncthreads();
  int base = (wv == 1) ? wcnt[0] : 0;
  if (keep) csrc[base + pos] = rsrc[tid];
  __syncthreads();
  int kd = wcnt[0] + wcnt[1];
  // rank-sort by src value (unique) -> deterministic reduction order
  if (tid < kd) {
    int sv = csrc[tid], r = 0;
    for (int q = 0; q < kd; ++q) r += (csrc[q] < sv) ? 1 : 0;
    rsrc[r] = sv;
  }
  __syncthreads();

  float ps0 = 0, pq0 = 0, ps1 = 0, pq1 = 0;   // BN partials (this thread's 2 batches)
  // each wave handles batches wv and wv+4 independently
  #pragma unroll
  for (int halfb = 0; halfb < 2; ++halfb) {
    int b = wv + halfb * 4;
    const float* sb = s + (size_t)b * NN * 8;
    f32x4 sd = *(const f32x4*)(sb + (size_t)d * 8 + 4);
    float v0 = -INFINITY, v1 = -INFINITY;
    if (lane < kd) {
      f32x4 ss = *(const f32x4*)(sb + (size_t)rsrc[lane] * 8);
      v0 = edge_e(ss, sd);
    }
    if (lane + 64 < kd) {
      f32x4 ss = *(const f32x4*)(sb + (size_t)rsrc[lane + 64] * 8);
      v1 = edge_e(ss, sd);
    }
    float m = fmaxf(v0, v1);
    #pragma unroll
    for (int off = 32; off > 0; off >>= 1) m = fmaxf(m, __shfl_xor(m, off, 64));
    float e0 = (lane < kd)      ? expf(v0 - m) : 0.0f;
    float e1 = (lane + 64 < kd) ? expf(v1 - m) : 0.0f;
    float sum = e0 + e1;
    #pragma unroll
    for (int off = 32; off > 0; off >>= 1) sum += __shfl_xor(sum, off, 64);
    float inv = (kd > 0) ? 1.0f / sum : 0.0f;
    swgt[wv][lane] = e0 * inv;
    swgt[wv][lane + 64] = e1 * inv;
    float a0 = 0.0f, a1 = 0.0f;
    const uint32* hb = hm32 + (size_t)b * NN * (CC / 2);
    #pragma unroll 4
    for (int j = 0; j < kd; ++j) {
      float w = swgt[wv][j];
      uint32 u = hb[(size_t)rsrc[j] * (CC / 2) + lane];
      a0 += w * bf2f((ushort)(u & 0xffffu));
      a1 += w * bf2f((ushort)(u >> 16));
    }
    ps0 += a0; pq0 += a0 * a0; ps1 += a1; pq1 += a1 * a1;
    uint32 o = (uint32)f2bf(a0) | ((uint32)f2bf(a1) << 16);
    hout[((size_t)b * NN + d) * (CC / 2) + lane] = o;
  }

  // block-reduce BN partials, fixed-point i64 atomic into bin d&7 (deterministic)
  f32x4 r; r[0] = ps0; r[1] = pq0; r[2] = ps1; r[3] = pq1;
  red[tid] = r;
  __syncthreads();
  if (wv == 0) {
    f32x4 t = red[lane] + red[lane + 64] + red[lane + 128] + red[lane + 192];
    u64* bb = bins + (size_t)(d & 7) * (CC * 2);
    atomicAdd(&bb[4 * lane + 0], (u64)(long long)llrint((double)t[0] * FPSCALE));
    atomicAdd(&bb[4 * lane + 1], (u64)(long long)llrint((double)t[1] * FPSCALE));
    atomicAdd(&bb[4 * lane + 2], (u64)(long long)llrint((double)t[2] * FPSCALE));
    atomicAdd(&bb[4 * lane + 3], (u64)(long long)llrint((double)t[3] * FPSCALE));
  }
}

// ---- BN finalize (per-block, redundant) + normalize + ELU ----
__global__ __launch_bounds__(256) void k_elu(const uint32* __restrict__ hout,
                                             const u64* __restrict__ bins,
                                             const float* __restrict__ gamma,
                                             const float* __restrict__ beta,
                                             float* __restrict__ out) {
  __shared__ float bsc[CC], bsh[CC];
  int tid = threadIdx.x;
  if (tid < CC) {
    long long S = 0, Q = 0;
    #pragma unroll
    for (int bin = 0; bin < 8; ++bin) {
      S += (long long)bins[bin * (CC * 2) + 2 * tid];
      Q += (long long)bins[bin * (CC * 2) + 2 * tid + 1];
    }
    double mean = (double)S / FPSCALE / (double)MROWS;
    double var  = (double)Q / FPSCALE / (double)MROWS - mean * mean;
    if (var < 0.0) var = 0.0;
    float scale = gamma[tid] / sqrtf((float)var + BN_EPS);
    bsc[tid] = scale;
    bsh[tid] = beta[tid] - (float)mean * scale;
  }
  __syncthreads();
  int pbase = blockIdx.x * 1024 + tid;
  #pragma unroll
  for (int i = 0; i < 4; ++i) {
    int p = pbase + i * 256;      // pair index
    int cp = p & 63;
    uint32 u = hout[p];
    float y0 = bf2f((ushort)(u & 0xffffu)) * bsc[2 * cp]     + bsh[2 * cp];
    float y1 = bf2f((ushort)(u >> 16))     * bsc[2 * cp + 1] + bsh[2 * cp + 1];
    float2 o;
    o.x = (y0 > 0.0f) ? y0 : expm1f(y0);
    o.y = (y1 > 0.0f) ? y1 : expm1f(y1);
    *(float2*)(out + 2 * (size_t)p) = o;
  }
}

extern "C" void kernel_launch(void* const* d_in, const int* in_sizes, int n_in,
                              void* d_out, int out_size, void* d_ws, size_t ws_size,
                              hipStream_t stream) {
  const float* x     = (const float*)d_in[0];
  const void*  ei    = d_in[1];
  const float* W     = (const float*)d_in[2];
  const float* a     = (const float*)d_in[3];
  const float* gamma = (const float*)d_in[4];
  const float* beta  = (const float*)d_in[5];
  float* out = (float*)d_out;

  char* p = (char*)d_ws;
  ushort* hm   = (ushort*)p; p += (size_t)MROWS * CC * 2;  // 4 MB (bf16)
  uint32* hout = (uint32*)p; p += (size_t)MROWS * CC * 2;  // 4 MB (bf16 pairs)
  float* s    = (float*)p; p += (size_t)MROWS * 8 * 4;     // 512 KB
  uint4* pack = (uint4*)p; p += (size_t)NFRAG * 16;        // 72 KB
  u64* bins   = (u64*)p;   p += 8 * CC * 2 * 8;            // 16 KB
  int* flag   = (int*)p;   p += 256;
  int* row_cnt  = (int*)p; p += NN * 4;
  int* row_src  = (int*)p; p += (size_t)NN * CAP * 4;      // 1 MB

  k_prep<<<32, 256, 0, stream>>>(W, a, (const int*)ei, pack, flag, row_cnt, bins);
  k_gemm<<<MROWS / 64, 256, 0, stream>>>(x, pack, ei, flag, hm, s, row_cnt, row_src);
  k_agg<<<NN, 256, 0, stream>>>(row_cnt, row_src, s, (const uint32*)hm, hout, bins);
  k_elu<<<(MROWS * CC / 2) / 1024, 256, 0, stream>>>(hout, bins, gamma, beta, out);
}

// Round 6
// 65.274 us; speedup vs baseline: 1.0705x; 1.0705x over previous
//
#include <hip/hip_runtime.h>
#include <hip/hip_bf16.h>
#include <math.h>

#define BB 8
#define NN 2048
#define INC 256
#define CC 128
#define NE 65536
#define CAP 128
#define MROWS (BB*NN)
#define BN_EPS 1e-5f
#define NT 9              // output col-tiles of 16 (8 -> hm, 1 -> s+pad)
#define NKC 8             // K chunks of 32 (K=256)
#define NFRAG (NT*NKC*64) // 4608 pre-packed fragments (72 KB)
#define FPSCALE 4194304.0 // 2^22 fixed-point scale for deterministic BN atomics

typedef unsigned int uint32;
typedef unsigned long long u64;
typedef __attribute__((ext_vector_type(8))) short short8;
typedef __attribute__((ext_vector_type(4))) float f32x4;

__device__ inline ushort f2bf(float f) {
  __hip_bfloat16 b = __float2bfloat16(f);   // HW cvt, RNE
  return reinterpret_cast<ushort&>(b);
}
__device__ inline float bf2f(ushort h) {
  return __uint_as_float(((uint32)h) << 16);
}

__device__ inline void load_edge(const void* ei, int is64, int e, int& s, int& d) {
  if (is64) {
    const long long* p = (const long long*)ei;
    s = (int)p[e]; d = (int)p[NE + e];
  } else {
    const int* p = (const int*)ei;
    s = p[e]; d = p[NE + e];
  }
}

// ---- prep: W -> packed MFMA fragments; detect int64; zero row_cnt + bins ----
// block m owns input rows [8m, 8m+8) == fragment k-slice (kc=m>>2, g=m&3).
__global__ __launch_bounds__(256) void k_prep(const float* __restrict__ W,
                                              const float* __restrict__ a,
                                              const int* __restrict__ ei32,
                                              uint4* __restrict__ pack,
                                              int* __restrict__ flag,
                                              int* __restrict__ row_cnt,
                                              u64* __restrict__ bins) {
  __shared__ float Wl[8][520];
  __shared__ float Wms[8][132];
  __shared__ float Was[8][8];
  __shared__ float av[256];
  int m = blockIdx.x, tid = threadIdx.x;
  if (m < 8) row_cnt[m * 256 + tid] = 0;
  if (m == 8) {
    #pragma unroll
    for (int i = 0; i < 8; ++i) bins[tid * 8 + i] = 0ull;
  }
  if (m == 0 && tid == 0) {
    int nz = 0;
    for (int t = 1; t < 128; t += 2) nz |= (ei32[t] != 0);
    *flag = nz ? 0 : 1;      // 1 => int64 layout
  }
  av[tid] = a[tid];
  const float4* Wg = (const float4*)(W + (size_t)m * 8 * 512);
  #pragma unroll
  for (int i = 0; i < 4; ++i) {
    int idx = tid + i * 256;           // 0..1023 float4s = 8 rows x 128
    int r = idx >> 7, c4 = idx & 127;
    *(float4*)&Wl[r][c4 * 4] = Wg[idx];
  }
  __syncthreads();
  {
    int c = tid & 127, half = tid >> 7;
    #pragma unroll
    for (int ii = 0; ii < 4; ++ii) {
      int r = half * 4 + ii;
      Wms[r][c] = 0.25f * (Wl[r][c] + Wl[r][128 + c] + Wl[r][256 + c] + Wl[r][384 + c]);
    }
  }
  {
    int i8 = tid >> 5, c2 = tid & 31;
    float p[8];
    #pragma unroll
    for (int j = 0; j < 8; ++j) p[j] = 0.0f;
    #pragma unroll
    for (int t4 = 0; t4 < 4; ++t4) {
      int cc = c2 + t4 * 32;
      float asrc = av[cc], adst = av[128 + cc];
      #pragma unroll
      for (int h = 0; h < 4; ++h) {
        float w = Wl[i8][h * 128 + cc];
        p[h] += w * asrc;
        p[4 + h] += w * adst;
      }
    }
    #pragma unroll
    for (int off = 16; off > 0; off >>= 1)
      #pragma unroll
      for (int j = 0; j < 8; ++j) p[j] += __shfl_xor(p[j], off, 64);
    if (c2 < 8) Was[i8][c2] = p[c2];
  }
  __syncthreads();
  if (tid < 144) {
    int t = tid >> 4, l16 = tid & 15;
    int cch = t * 16 + l16;
    int kc = m >> 2, g = m & 3;
    uint32 h[8];
    #pragma unroll
    for (int j = 0; j < 8; ++j) {
      float v = 0.0f;
      if (cch < CC) v = Wms[j][cch];
      else if (cch < CC + 8) v = Was[j][cch - CC];
      h[j] = (uint32)f2bf(v);
    }
    uint4 u;
    u.x = h[0] | (h[1] << 16);
    u.y = h[2] | (h[3] << 16);
    u.z = h[4] | (h[5] << 16);
    u.w = h[6] | (h[7] << 16);
    pack[(t * NKC + kc) * 64 + g * 16 + l16] = u;
  }
}

// ---- MFMA GEMM + edge-list build ----
// 512 threads = 8 waves: row-tile rt=wv&3 (16 rows), t-half th=wv>>2.
// pack staged once into LDS; 2 blocks/CU -> 16 waves/CU.
__global__ __launch_bounds__(512) void k_gemm(const float* __restrict__ x,
                                              const uint4* __restrict__ pack,
                                              const void* __restrict__ ei,
                                              const int* __restrict__ flag,
                                              ushort* __restrict__ hm,
                                              float* __restrict__ s,
                                              int* __restrict__ row_cnt,
                                              int* __restrict__ row_src) {
  __shared__ uint4 lp[NFRAG];   // 72 KB
  int tid = threadIdx.x;
  // edge-list build: this block's 256 edges
  if (tid < 256) {
    int e = blockIdx.x * 256 + tid;
    int is64 = *flag;
    int src, dst;
    load_edge(ei, is64, e, src, dst);
    int pos = atomicAdd(&row_cnt[dst], 1);
    if (pos < CAP) row_src[dst * CAP + pos] = src;
  }
  // stage fragments -> LDS (9 sweeps x 8 KB)
  #pragma unroll
  for (int i = 0; i < 9; ++i) lp[i * 512 + tid] = pack[i * 512 + tid];

  int lane = tid & 63, wv = tid >> 6;
  int rt = wv & 3, th = wv >> 2;
  int g = lane >> 4;
  int xrow = blockIdx.x * 64 + rt * 16 + (lane & 15);
  const float* xr = x + (size_t)xrow * INC;

  short8 xf[8];
  #pragma unroll
  for (int kc = 0; kc < 8; ++kc) {
    f32x4 xa = *(const f32x4*)(xr + kc * 32 + g * 8);
    f32x4 xb = *(const f32x4*)(xr + kc * 32 + g * 8 + 4);
    short8 t;
    t[0] = (short)f2bf(xa[0]); t[1] = (short)f2bf(xa[1]);
    t[2] = (short)f2bf(xa[2]); t[3] = (short)f2bf(xa[3]);
    t[4] = (short)f2bf(xb[0]); t[5] = (short)f2bf(xb[1]);
    t[6] = (short)f2bf(xb[2]); t[7] = (short)f2bf(xb[3]);
    xf[kc] = t;
  }
  __syncthreads();

  f32x4 acc[4];
  f32x4 accE = (f32x4)(0.0f);
  #pragma unroll
  for (int i = 0; i < 4; ++i) acc[i] = (f32x4)(0.0f);

  const short8* fr = (const short8*)lp;
  int tb = th * 4;
  #pragma unroll
  for (int kc = 0; kc < NKC; ++kc) {
    #pragma unroll
    for (int i = 0; i < 4; ++i) {
      short8 af = fr[((tb + i) * NKC + kc) * 64 + lane];
      acc[i] = __builtin_amdgcn_mfma_f32_16x16x32_bf16(af, xf[kc], acc[i], 0, 0, 0);
    }
    short8 ae = fr[(8 * NKC + kc) * 64 + lane];
    accE = __builtin_amdgcn_mfma_f32_16x16x32_bf16(ae, xf[kc], accE, 0, 0, 0);
  }

  // D layout: row(ch-in-tile) = 4*g + reg, col(xrow-in-wave) = lane&15
  ushort* hrow = hm + (size_t)xrow * CC;
  #pragma unroll
  for (int i = 0; i < 4; ++i) {
    int t = tb + i;
    uint32 p0 = (uint32)f2bf(acc[i][0]) | ((uint32)f2bf(acc[i][1]) << 16);
    uint32 p1 = (uint32)f2bf(acc[i][2]) | ((uint32)f2bf(acc[i][3]) << 16);
    *(uint2*)(hrow + t * 16 + g * 4) = make_uint2(p0, p1);
  }
  if (th == 1 && g < 2) {
    *(f32x4*)(s + (size_t)xrow * 8 + g * 4) = accE;
  }
}

__device__ inline float edge_e(f32x4 ss, f32x4 sd) {
  float sum = 0.0f;
  #pragma unroll
  for (int h = 0; h < 4; ++h) {
    float v = ss[h] + sd[h];
    sum += (v > 0.0f) ? v : 0.2f * v;
  }
  return 0.25f * sum;
}

// ---- fused dedupe+sort+e+softmax+aggregate+BN-partials: one block per dst row ----
// each wave handles TWO batches (wv, wv+4) with interleaved gather streams.
__global__ __launch_bounds__(256) void k_agg(const int* __restrict__ row_cnt,
                                             const int* __restrict__ row_src,
                                             const float* __restrict__ s,
                                             const uint32* __restrict__ hm32,
                                             uint32* __restrict__ hout,
                                             u64* __restrict__ bins) {
  __shared__ int rsrc[CAP], csrc[CAP];
  __shared__ float swgt[8][CAP];
  __shared__ f32x4 red[256];
  __shared__ int wcnt[2];
  int d = blockIdx.x, tid = threadIdx.x;
  int lane = tid & 63, wv = tid >> 6;
  int k0 = row_cnt[d]; if (k0 > CAP) k0 = CAP;

  if (tid < k0) rsrc[tid] = row_src[d * CAP + tid];
  __syncthreads();
  // dedupe by src (duplicate (src,dst) edges have identical e-values; set suffices)
  int keep = 0;
  if (tid < k0) {
    keep = 1;
    int sv = rsrc[tid];
    for (int q = 0; q < tid; ++q) if (rsrc[q] == sv) { keep = 0; break; }
  }
  u64 mask = __ballot(keep);
  int pos = __popcll(mask & ((1ull << lane) - 1ull));
  if (lane == 0 && wv < 2) wcnt[wv] = (int)__popcll(mask);
  __syncthreads();
  int base = (wv == 1) ? wcnt[0] : 0;
  if (keep) csrc[base + pos] = rsrc[tid];
  __syncthreads();
  int kd = wcnt[0] + wcnt[1];
  // rank-sort by src value (unique) -> deterministic reduction order
  if (tid < kd) {
    int sv = csrc[tid], r = 0;
    for (int q = 0; q < kd; ++q) r += (csrc[q] < sv) ? 1 : 0;
    rsrc[r] = sv;
  }
  __syncthreads();

  int b0 = wv, b1 = wv + 4;
  const float* sb0 = s + (size_t)b0 * NN * 8;
  const float* sb1 = s + (size_t)b1 * NN * 8;
  f32x4 sd0 = *(const f32x4*)(sb0 + (size_t)d * 8 + 4);
  f32x4 sd1 = *(const f32x4*)(sb1 + (size_t)d * 8 + 4);
  float v00 = -INFINITY, v01 = -INFINITY, v10 = -INFINITY, v11 = -INFINITY;
  if (lane < kd) {
    int r = rsrc[lane];
    f32x4 s0 = *(const f32x4*)(sb0 + (size_t)r * 8);
    f32x4 s1 = *(const f32x4*)(sb1 + (size_t)r * 8);
    v00 = edge_e(s0, sd0);
    v10 = edge_e(s1, sd1);
  }
  if (lane + 64 < kd) {
    int r = rsrc[lane + 64];
    f32x4 s0 = *(const f32x4*)(sb0 + (size_t)r * 8);
    f32x4 s1 = *(const f32x4*)(sb1 + (size_t)r * 8);
    v01 = edge_e(s0, sd0);
    v11 = edge_e(s1, sd1);
  }
  float m0 = fmaxf(v00, v01), m1 = fmaxf(v10, v11);
  #pragma unroll
  for (int off = 32; off > 0; off >>= 1) {
    m0 = fmaxf(m0, __shfl_xor(m0, off, 64));
    m1 = fmaxf(m1, __shfl_xor(m1, off, 64));
  }
  float e00 = (lane < kd)      ? expf(v00 - m0) : 0.0f;
  float e01 = (lane + 64 < kd) ? expf(v01 - m0) : 0.0f;
  float e10 = (lane < kd)      ? expf(v10 - m1) : 0.0f;
  float e11 = (lane + 64 < kd) ? expf(v11 - m1) : 0.0f;
  float sum0 = e00 + e01, sum1 = e10 + e11;
  #pragma unroll
  for (int off = 32; off > 0; off >>= 1) {
    sum0 += __shfl_xor(sum0, off, 64);
    sum1 += __shfl_xor(sum1, off, 64);
  }
  float inv0 = (kd > 0) ? 1.0f / sum0 : 0.0f;
  float inv1 = (kd > 0) ? 1.0f / sum1 : 0.0f;
  swgt[wv][lane]      = e00 * inv0;
  swgt[wv][lane + 64] = e01 * inv0;
  swgt[b1][lane]      = e10 * inv1;
  swgt[b1][lane + 64] = e11 * inv1;

  float a0 = 0.0f, a1 = 0.0f, a2 = 0.0f, a3 = 0.0f;
  const uint32* hb0 = hm32 + (size_t)b0 * NN * (CC / 2);
  const uint32* hb1 = hm32 + (size_t)b1 * NN * (CC / 2);
  #pragma unroll 4
  for (int j = 0; j < kd; ++j) {
    int r = rsrc[j];
    float w0 = swgt[wv][j], w1 = swgt[b1][j];
    uint32 u0 = hb0[(size_t)r * (CC / 2) + lane];
    uint32 u1 = hb1[(size_t)r * (CC / 2) + lane];
    a0 += w0 * bf2f((ushort)(u0 & 0xffffu));
    a1 += w0 * bf2f((ushort)(u0 >> 16));
    a2 += w1 * bf2f((ushort)(u1 & 0xffffu));
    a3 += w1 * bf2f((ushort)(u1 >> 16));
  }
  hout[((size_t)b0 * NN + d) * (CC / 2) + lane] =
      (uint32)f2bf(a0) | ((uint32)f2bf(a1) << 16);
  hout[((size_t)b1 * NN + d) * (CC / 2) + lane] =
      (uint32)f2bf(a2) | ((uint32)f2bf(a3) << 16);

  // block-reduce BN partials, fixed-point i64 atomic into bin d&7 (deterministic)
  f32x4 r4;
  r4[0] = a0 + a2; r4[1] = a0 * a0 + a2 * a2;
  r4[2] = a1 + a3; r4[3] = a1 * a1 + a3 * a3;
  red[tid] = r4;
  __syncthreads();
  if (wv == 0) {
    f32x4 t = red[lane] + red[lane + 64] + red[lane + 128] + red[lane + 192];
    u64* bb = bins + (size_t)(d & 7) * (CC * 2);
    atomicAdd(&bb[4 * lane + 0], (u64)(long long)llrint((double)t[0] * FPSCALE));
    atomicAdd(&bb[4 * lane + 1], (u64)(long long)llrint((double)t[1] * FPSCALE));
    atomicAdd(&bb[4 * lane + 2], (u64)(long long)llrint((double)t[2] * FPSCALE));
    atomicAdd(&bb[4 * lane + 3], (u64)(long long)llrint((double)t[3] * FPSCALE));
  }
}

// ---- BN finalize (per-block, redundant) + normalize + ELU ----
__global__ __launch_bounds__(256) void k_elu(const uint32* __restrict__ hout,
                                             const u64* __restrict__ bins,
                                             const float* __restrict__ gamma,
                                             const float* __restrict__ beta,
                                             float* __restrict__ out) {
  __shared__ float bsc[CC], bsh[CC];
  int tid = threadIdx.x;
  if (tid < CC) {
    long long S = 0, Q = 0;
    #pragma unroll
    for (int bin = 0; bin < 8; ++bin) {
      S += (long long)bins[bin * (CC * 2) + 2 * tid];
      Q += (long long)bins[bin * (CC * 2) + 2 * tid + 1];
    }
    double mean = (double)S / FPSCALE / (double)MROWS;
    double var  = (double)Q / FPSCALE / (double)MROWS - mean * mean;
    if (var < 0.0) var = 0.0;
    float scale = gamma[tid] / sqrtf((float)var + BN_EPS);
    bsc[tid] = scale;
    bsh[tid] = beta[tid] - (float)mean * scale;
  }
  __syncthreads();
  int pbase = blockIdx.x * 1024 + tid;
  #pragma unroll
  for (int i = 0; i < 4; ++i) {
    int p = pbase + i * 256;      // pair index
    int cp = p & 63;
    uint32 u = hout[p];
    float y0 = bf2f((ushort)(u & 0xffffu)) * bsc[2 * cp]     + bsh[2 * cp];
    float y1 = bf2f((ushort)(u >> 16))     * bsc[2 * cp + 1] + bsh[2 * cp + 1];
    float2 o;
    o.x = (y0 > 0.0f) ? y0 : expm1f(y0);
    o.y = (y1 > 0.0f) ? y1 : expm1f(y1);
    *(float2*)(out + 2 * (size_t)p) = o;
  }
}

extern "C" void kernel_launch(void* const* d_in, const int* in_sizes, int n_in,
                              void* d_out, int out_size, void* d_ws, size_t ws_size,
                              hipStream_t stream) {
  const float* x     = (const float*)d_in[0];
  const void*  ei    = d_in[1];
  const float* W     = (const float*)d_in[2];
  const float* a     = (const float*)d_in[3];
  const float* gamma = (const float*)d_in[4];
  const float* beta  = (const float*)d_in[5];
  float* out = (float*)d_out;

  char* p = (char*)d_ws;
  ushort* hm   = (ushort*)p; p += (size_t)MROWS * CC * 2;  // 4 MB (bf16)
  uint32* hout = (uint32*)p; p += (size_t)MROWS * CC * 2;  // 4 MB (bf16 pairs)
  float* s    = (float*)p; p += (size_t)MROWS * 8 * 4;     // 512 KB
  uint4* pack = (uint4*)p; p += (size_t)NFRAG * 16;        // 72 KB
  u64* bins   = (u64*)p;   p += 8 * CC * 2 * 8;            // 16 KB
  int* flag   = (int*)p;   p += 256;
  int* row_cnt  = (int*)p; p += NN * 4;
  int* row_src  = (int*)p; p += (size_t)NN * CAP * 4;      // 1 MB

  k_prep<<<32, 256, 0, stream>>>(W, a, (const int*)ei, pack, flag, row_cnt, bins);
  k_gemm<<<MROWS / 64, 512, 0, stream>>>(x, pack, ei, flag, hm, s, row_cnt, row_src);
  k_agg<<<NN, 256, 0, stream>>>(row_cnt, row_src, s, (const uint32*)hm, hout, bins);
  k_elu<<<(MROWS * CC / 2) / 1024, 256, 0, stream>>>(hout, bins, gamma, beta, out);
}